// Round 1
// baseline (29.053 us; speedup 1.0000x reference)
//
#include <hip/hip_runtime.h>
#include <cstdint>
#include <cstddef>

#define MM 36
#define NP 10

__device__ __forceinline__ float pwl_eval(const float2* __restrict__ Trow, float x) {
    float xd = x * 16.0f;
    float fip = floorf(xd);
    float frac = xd - fip;
    int ip = (int)fip;
    ip = ip < 0 ? 0 : (ip > 16 ? 16 : ip);
    float2 t = Trow[ip];
    return t.x + frac * t.y;   // cs[ip] + frac * nw[min(ip+1,16)]
}

__global__ __launch_bounds__(64) void count_kernel(
    const float* __restrict__ boxes,      // [B,4,36]
    const float* __restrict__ attention,  // [B,36]
    const float* __restrict__ fw,         // [8,17]
    float* __restrict__ out,              // [B,11]
    int B)
{
    __shared__ float2 T[8][17];  // (cs[k], nw[min(k+1,16)]) per function

    const int tid = threadIdx.x;
    const int b = blockIdx.x * 64 + tid;

    // ---- build pwl tables (threads 0..7, one function each) ----
    if (tid < 8) {
        const float* w = fw + tid * 17;
        float aw[17];
        float s = 0.f;
        #pragma unroll
        for (int k = 0; k < 17; ++k) { aw[k] = fabsf(w[k]); s += aw[k]; }
        float nw[17];
        #pragma unroll
        for (int k = 0; k < 17; ++k) nw[k] = aw[k] / s;
        float c = 0.f;
        #pragma unroll
        for (int k = 0; k < 17; ++k) {
            c += nw[k];
            T[tid][k] = make_float2(c, (k < 16) ? nw[k + 1] : nw[16]);
        }
    }

    // ---- load attention row (overlaps with table build) ----
    float v[MM];
    if (b < B) {
        const float4* ap = reinterpret_cast<const float4*>(attention + (size_t)b * MM);
        #pragma unroll
        for (int q = 0; q < MM / 4; ++q) {
            float4 t = ap[q];
            v[q * 4 + 0] = t.x; v[q * 4 + 1] = t.y;
            v[q * 4 + 2] = t.z; v[q * 4 + 3] = t.w;
        }
    }
    __syncthreads();
    if (b >= B) return;

    // ---- top-10 set selection (strict >, mask; ties -> lowest index == lax.top_k set) ----
    unsigned long long selmask = 0ull;
    #pragma unroll
    for (int k = 0; k < NP; ++k) {
        float mx = -3.0e38f; int mi = 0;
        #pragma unroll
        for (int m = 0; m < MM; ++m) {
            bool avail = ((selmask >> m) & 1ull) == 0ull;
            bool better = avail && (v[m] > mx);
            mx = better ? v[m] : mx;
            mi = better ? m : mi;
        }
        selmask |= (1ull << mi);
    }
    // compact selected indices into 6-bit fields (order irrelevant downstream)
    unsigned long long packed = 0ull;
    int cnt = 0;
    #pragma unroll
    for (int m = 0; m < MM; ++m) {
        if ((selmask >> m) & 1ull) {
            packed |= ((unsigned long long)m) << (6 * cnt);
            ++cnt;
        }
    }

    // ---- gather selected attention + box coords (L1/L2-warm) ----
    const float* arow = attention + (size_t)b * MM;
    const float* brow = boxes + (size_t)b * (4 * MM);
    float satt[NP], y1[NP], x1[NP], y2[NP], x2[NP], area[NP];
    #pragma unroll
    for (int k = 0; k < NP; ++k) {
        int mk = (int)((packed >> (6 * k)) & 63ull);
        float av = arow[mk];
        satt[k] = 1.0f / (1.0f + __expf(-av));   // sigmoid
        float a0 = brow[mk];
        float a1 = brow[mk + MM];
        float a2 = brow[mk + 2 * MM];
        float a3 = brow[mk + 3 * MM];
        y1[k] = a0; x1[k] = a1; y2[k] = a2; x2[k] = a3;
        area[k] = fmaxf(a2 - a0, 0.f) * fmaxf(a3 - a1, 0.f);
    }

    // prod over the zero score_diff: f2(1.0)^NP = cs2[16]^10
    float cs2_16 = T[2][16].x;
    float p2 = cs2_16 * cs2_16;
    float p4 = p2 * p2;
    float p8 = p4 * p4;
    float P = p8 * p2;

    const float2* T0 = &T[0][0];
    const float2* T1 = &T[1][0];
    const float2* T2 = &T[2][0];
    const float2* T5 = &T[5][0];
    const float2* T6 = &T[6][0];
    const float2* T7 = &T[7][0];

    // ---- pair loop (upper triangle incl. diag), symmetric weighting ----
    float s_row[NP];
    #pragma unroll
    for (int i = 0; i < NP; ++i) s_row[i] = 0.f;
    float at[NP * (NP + 1) / 2];
    float pd_sum = 0.f;

    #pragma unroll
    for (int i = 0; i < NP; ++i) {
        #pragma unroll
        for (int j = i; j < NP; ++j) {
            const int p = i * NP - (i * (i + 1)) / 2 + j;  // compile-time
            float ty = fmaxf(y1[i], y1[j]);
            float tx = fmaxf(x1[i], x1[j]);
            float by = fminf(y2[i], y2[j]);
            float bx = fminf(x2[i], x2[j]);
            float ih = fmaxf(by - ty, 0.f);
            float iw = fmaxf(bx - tx, 0.f);
            float inter = ih * iw;
            float iouv = __fdividef(inter, area[i] + area[j] - inter + 1e-12f);
            float Dm = fmaxf(1.0f - iouv, 0.0f);
            float A = satt[i] * satt[j];
            float a_t = pwl_eval(T0, A) * pwl_eval(T1, Dm);
            float simv = pwl_eval(T2, 1.0f - fabsf(satt[i] - satt[j])) * P;
            float pdv = fabsf(pwl_eval(T6, Dm) - 0.5f);
            at[p] = a_t;
            s_row[i] += simv;
            if (j > i) { s_row[j] += simv; pd_sum += 2.f * pdv; }
            else       { pd_sum += pdv; }
        }
    }

    float inv[NP];
    #pragma unroll
    for (int i = 0; i < NP; ++i) inv[i] = 1.0f / s_row[i];

    float score_sum = 0.f;
    #pragma unroll
    for (int i = 0; i < NP; ++i) {
        #pragma unroll
        for (int j = i; j < NP; ++j) {
            const int p = i * NP - (i * (i + 1)) / 2 + j;
            float sc = at[p] * inv[i] * inv[j];
            score_sum += (j > i) ? 2.f * sc : sc;
        }
    }

    float corr_sum = 0.f, pa_sum = 0.f;
    #pragma unroll
    for (int i = 0; i < NP; ++i) {
        corr_sum += pwl_eval(T0, satt[i] * satt[i]) * inv[i];
        pa_sum += fabsf(pwl_eval(T5, satt[i]) - 0.5f);
    }

    float gate = pwl_eval(T7, pa_sum * (1.0f / NP) + pd_sum * (1.0f / (NP * NP)));

    float mod_E = score_sum + corr_sum;
    float cval = sqrtf(mod_E + 1e-20f);
    cval = fminf(fmaxf(cval, 0.f), 10.0f);
    float fip = floorf(cval);
    int ipc = (int)fip;
    float frac = cval - fip;
    int i0 = ipc < 10 ? ipc : 10;
    int i1 = (ipc + 1) < 10 ? (ipc + 1) : 10;

    float* orow = out + (size_t)b * (NP + 1);
    #pragma unroll
    for (int k = 0; k <= NP; ++k) {
        float val = 0.f;
        val += (k == i0) ? (1.0f - frac) * gate : 0.f;
        val += (k == i1) ? frac * gate : 0.f;
        orow[k] = val;
    }
}

extern "C" void kernel_launch(void* const* d_in, const int* in_sizes, int n_in,
                              void* d_out, int out_size, void* d_ws, size_t ws_size,
                              hipStream_t stream) {
    const float* boxes = (const float*)d_in[0];
    const float* attention = (const float*)d_in[1];
    const float* fw = (const float*)d_in[2];
    float* out = (float*)d_out;
    int B = in_sizes[1] / MM;   // 32768
    int grid = (B + 63) / 64;
    hipLaunchKernelGGL(count_kernel, dim3(grid), dim3(64), 0, stream,
                       boxes, attention, fw, out, B);
}

// Round 2
// 28.730 us; speedup vs baseline: 1.0112x; 1.0112x over previous
//
#include <hip/hip_runtime.h>
#include <cstdint>
#include <cstddef>

#define MM 36
#define NP 10
#define BLOCK 256   // 4 waves, 16 batches/block (16 lanes per batch)

__device__ __forceinline__ float pwl_eval(const float2* __restrict__ Trow, float x) {
    float xd = x * 16.0f;
    float fip = floorf(xd);
    float frac = xd - fip;
    int ip = (int)fip;
    ip = ip < 0 ? 0 : (ip > 16 ? 16 : ip);
    float2 t = Trow[ip];
    return t.x + frac * t.y;   // cs[ip] + frac * nw[min(ip+1,16)]
}

__device__ __forceinline__ unsigned long long umax64(unsigned long long a, unsigned long long b) {
    return a > b ? a : b;
}

// order-preserving float->uint map; key = (ord(v)<<32) | (63-m)
// max key == max value, ties -> lowest index (stable top_k semantics)
__device__ __forceinline__ unsigned long long pack_key(float v, int m) {
    unsigned u = __float_as_uint(v);
    u = ((int)u < 0) ? ~u : (u | 0x80000000u);
    return ((unsigned long long)u << 32) | (unsigned)(63 - m);
}

__global__ __launch_bounds__(BLOCK, 4) void count_kernel(
    const float* __restrict__ boxes,      // [B,4,36]
    const float* __restrict__ attention,  // [B,36]
    const float* __restrict__ fw,         // [8,17]
    float* __restrict__ out,              // [B,11]
    int B)
{
    __shared__ float2 T[8][17];  // (cs[k], nw[min(k+1,16)]) per function

    const int tid = threadIdx.x;

    // ---- build pwl tables (threads 0..7, one function each) ----
    if (tid < 8) {
        const float* w = fw + tid * 17;
        float aw[17];
        float s = 0.f;
        #pragma unroll
        for (int k = 0; k < 17; ++k) { aw[k] = fabsf(w[k]); s += aw[k]; }
        float nw[17];
        #pragma unroll
        for (int k = 0; k < 17; ++k) nw[k] = aw[k] / s;
        float c = 0.f;
        #pragma unroll
        for (int k = 0; k < 17; ++k) {
            c += nw[k];
            T[tid][k] = make_float2(c, (k < 16) ? nw[k + 1] : nw[16]);
        }
    }
    __syncthreads();

    const int lane = tid & 63;           // lane in wave
    const int l    = lane & 15;          // lane in 16-lane group
    const int b    = blockIdx.x * (BLOCK / 16) + (tid >> 4);
    if (b >= B) return;

    const float* arow = attention + (size_t)b * MM;
    const float* brow = boxes + (size_t)b * (4 * MM);

    // ---- lane-parallel top-10 (u64 keys, butterfly max over 16 lanes) ----
    unsigned long long k0 = pack_key(arow[l], l);
    unsigned long long k1 = pack_key(arow[l + 16], l + 16);
    unsigned long long k2 = (l < 4) ? pack_key(arow[l + 32], l + 32) : 0ull;

    unsigned long long packed = 0ull;    // 10 x 6-bit selected indices (same in all lanes)
    #pragma unroll
    for (int t = 0; t < NP; ++t) {
        unsigned long long km = umax64(umax64(k0, k1), k2);
        km = umax64(km, __shfl_xor(km, 1));
        km = umax64(km, __shfl_xor(km, 2));
        km = umax64(km, __shfl_xor(km, 4));
        km = umax64(km, __shfl_xor(km, 8));
        int mt = 63 - (int)(km & 63ull);
        packed |= ((unsigned long long)mt) << (6 * t);
        k0 = (mt == l)      ? 0ull : k0;
        k1 = (mt == l + 16) ? 0ull : k1;
        k2 = (mt == l + 32) ? 0ull : k2;
    }

    // ---- gather all 10 selected proposals (statically indexed arrays) ----
    float satt[NP], y1[NP], x1[NP], y2[NP], x2[NP], area[NP], at[NP];
    #pragma unroll
    for (int t = 0; t < NP; ++t) {
        int m = (int)((packed >> (6 * t)) & 63ull);
        float av = arow[m];
        satt[t] = 1.0f / (1.0f + __expf(-av));
        float a0 = brow[m];
        float a1 = brow[m + MM];
        float a2 = brow[m + 2 * MM];
        float a3 = brow[m + 3 * MM];
        y1[t] = a0; x1[t] = a1; y2[t] = a2; x2[t] = a3;
        area[t] = fmaxf(a2 - a0, 0.f) * fmaxf(a3 - a1, 0.f);
        at[t] = 0.f;
    }

    // f2(1.0)^NP (score_diff is identically zero in the reference)
    float cs2_16 = T[2][16].x;
    float p2 = cs2_16 * cs2_16;
    float p4 = p2 * p2;
    float p8 = p4 * p4;
    float P = p8 * p2;

    const float2* T0 = &T[0][0];
    const float2* T1 = &T[1][0];
    const float2* T2 = &T[2][0];
    const float2* T5 = &T[5][0];
    const float2* T6 = &T[6][0];
    const float2* T7 = &T[7][0];

    // ---- row phase: lane l owns row i=l of the full 10x10 matrix ----
    float s_i = 0.f, pd_i = 0.f, pa_i = 0.f;
    float sattI = 0.f;
    if (l < NP) {
        int mo = (int)((packed >> (6 * l)) & 63ull);
        float av = arow[mo];
        sattI = 1.0f / (1.0f + __expf(-av));
        float y1I = brow[mo];
        float x1I = brow[mo + MM];
        float y2I = brow[mo + 2 * MM];
        float x2I = brow[mo + 3 * MM];
        float areaI = fmaxf(y2I - y1I, 0.f) * fmaxf(x2I - x1I, 0.f);

        #pragma unroll
        for (int j = 0; j < NP; ++j) {
            float ty = fmaxf(y1I, y1[j]);
            float tx = fmaxf(x1I, x1[j]);
            float by = fminf(y2I, y2[j]);
            float bx = fminf(x2I, x2[j]);
            float ih = fmaxf(by - ty, 0.f);
            float iw = fmaxf(bx - tx, 0.f);
            float inter = ih * iw;
            float iouv = __fdividef(inter, areaI + area[j] - inter + 1e-12f);
            float Dm = fmaxf(1.0f - iouv, 0.0f);
            float A = sattI * satt[j];
            at[j] = pwl_eval(T0, A) * pwl_eval(T1, Dm);
            s_i += pwl_eval(T2, 1.0f - fabsf(sattI - satt[j])) * P;
            pd_i += fabsf(pwl_eval(T6, Dm) - 0.5f);
        }
        pa_i = fabsf(pwl_eval(T5, sattI) - 0.5f);
    }

    // ---- cross-lane: inv_j broadcast, score dot, group sums (all lanes active) ----
    float inv_i = 1.0f / s_i;            // garbage on lanes >= NP (masked below)
    const int gbase = lane & 48;
    float dot = 0.f;
    #pragma unroll
    for (int j = 0; j < NP; ++j) {
        float ivj = __shfl(inv_i, gbase + j);
        dot = fmaf(at[j], ivj, dot);
    }
    float score_i = inv_i * dot;
    float corr_i = pwl_eval(T0, sattI * sattI) * inv_i;
    float contrib = (l < NP) ? (score_i + corr_i) : 0.f;

    #pragma unroll
    for (int s = 1; s < 16; s <<= 1) {
        contrib += __shfl_xor(contrib, s);
        pa_i    += __shfl_xor(pa_i, s);
        pd_i    += __shfl_xor(pd_i, s);
    }

    // ---- epilogue: gate, sqrt, one-hot interp; lanes 0..10 write ----
    float gate = pwl_eval(T7, pa_i * 0.1f + pd_i * 0.01f);
    float cval = sqrtf(contrib + 1e-20f);
    cval = fminf(fmaxf(cval, 0.f), 10.0f);
    float fip = floorf(cval);
    int ipc = (int)fip;
    float frac = cval - fip;
    int i0 = ipc < 10 ? ipc : 10;
    int i1 = (ipc + 1) < 10 ? (ipc + 1) : 10;

    if (l < NP + 1) {
        float val = ((l == i0) ? (1.0f - frac) * gate : 0.f)
                  + ((l == i1) ? frac * gate : 0.f);
        out[(size_t)b * (NP + 1) + l] = val;
    }
}

extern "C" void kernel_launch(void* const* d_in, const int* in_sizes, int n_in,
                              void* d_out, int out_size, void* d_ws, size_t ws_size,
                              hipStream_t stream) {
    const float* boxes = (const float*)d_in[0];
    const float* attention = (const float*)d_in[1];
    const float* fw = (const float*)d_in[2];
    float* out = (float*)d_out;
    int B = in_sizes[1] / MM;   // 32768
    int batches_per_block = BLOCK / 16;
    int grid = (B + batches_per_block - 1) / batches_per_block;
    hipLaunchKernelGGL(count_kernel, dim3(grid), dim3(BLOCK), 0, stream,
                       boxes, attention, fw, out, B);
}

// Round 3
// 24.640 us; speedup vs baseline: 1.1791x; 1.1660x over previous
//
#include <hip/hip_runtime.h>
#include <cstdint>
#include <cstddef>

#define MM 36
#define NP 10
#define BLOCK 256
#define GPB (BLOCK / 16)   // 16 batches (groups) per block

// ---- DPP helpers: 16-lane butterfly reduce, zero LDS traffic ----
template<int CTRL>
__device__ __forceinline__ float dpp_movf(float x) {
    return __int_as_float(__builtin_amdgcn_update_dpp(
        0, __float_as_int(x), CTRL, 0xF, 0xF, true));
}
__device__ __forceinline__ float rowmax16(float x) {
    x = fmaxf(x, dpp_movf<0xB1>(x));   // quad_perm [1,0,3,2]  (xor 1)
    x = fmaxf(x, dpp_movf<0x4E>(x));   // quad_perm [2,3,0,1]  (xor 2)
    x = fmaxf(x, dpp_movf<0x141>(x));  // row_half_mirror      (fold 8)
    x = fmaxf(x, dpp_movf<0x140>(x));  // row_mirror           (fold 16)
    return x;
}
__device__ __forceinline__ float rowsum16(float x) {
    x += dpp_movf<0xB1>(x);
    x += dpp_movf<0x4E>(x);
    x += dpp_movf<0x141>(x);
    x += dpp_movf<0x140>(x);
    return x;
}

__device__ __forceinline__ float pwl_eval(const float2* __restrict__ Trow, float x) {
    float xd = x * 16.0f;
    float fip = floorf(xd);
    float frac = xd - fip;
    int ip = (int)fip;
    ip = ip < 0 ? 0 : (ip > 16 ? 16 : ip);
    float2 t = Trow[ip];
    return t.x + frac * t.y;   // cs[ip] + frac * nw[min(ip+1,16)]
}

__global__ __launch_bounds__(BLOCK) void count_kernel(
    const float* __restrict__ boxes,      // [B,4,36]
    const float* __restrict__ attention,  // [B,36]
    const float* __restrict__ fw,         // [8,17]
    float* __restrict__ out,              // [B,11]
    int B)
{
    __shared__ float2 T[8][17];                       // pwl tables
    __shared__ float2 prop[GPB][NP][3];               // (y1,x1),(y2,x2),(area,satt)
    __shared__ __align__(8) float invl[GPB][NP];      // 1/s_i per proposal

    const int tid = threadIdx.x;

    // ---- build pwl tables (threads 0..7) ----
    if (tid < 8) {
        const float* w = fw + tid * 17;
        float aw[17];
        float s = 0.f;
        #pragma unroll
        for (int k = 0; k < 17; ++k) { aw[k] = fabsf(w[k]); s += aw[k]; }
        float nw[17];
        #pragma unroll
        for (int k = 0; k < 17; ++k) nw[k] = aw[k] / s;
        float c = 0.f;
        #pragma unroll
        for (int k = 0; k < 17; ++k) {
            c += nw[k];
            T[tid][k] = make_float2(c, (k < 16) ? nw[k + 1] : nw[16]);
        }
    }

    const int lane = tid & 63;
    const int l    = tid & 15;     // lane within 16-lane group (one DPP row)
    const int g    = tid >> 4;     // group within block
    int b = blockIdx.x * GPB + g;
    const bool valid = (b < B);
    b = valid ? b : (B - 1);

    const float* arow = attention + (size_t)b * MM;
    const float* brow = boxes + (size_t)b * (4 * MM);

    // issue attention loads before the barrier (overlap table build)
    float v0 = arow[l];
    float v1 = arow[l + 16];
    float v2 = (l < 4) ? arow[l + 32] : -INFINITY;

    __syncthreads();

    // ---- top-10: DPP max + ballot argmax (ties -> lowest index, == lax.top_k set) ----
    unsigned long long packed = 0ull;
    const int gbase = lane & 48;
    #pragma unroll
    for (int t = 0; t < NP; ++t) {
        float vm = rowmax16(fmaxf(fmaxf(v0, v1), v2));
        unsigned long long b0 = __ballot(v0 == vm);
        unsigned long long b1 = __ballot(v1 == vm);
        unsigned long long b2 = __ballot(v2 == vm);
        unsigned g0 = (unsigned)((b0 >> gbase) & 0xFFFFull);
        unsigned g1 = (unsigned)((b1 >> gbase) & 0xFFFFull);
        unsigned g2 = (unsigned)((b2 >> gbase) & 0xFFFFull);
        int m = g0 ? (__ffs(g0) - 1)
              : (g1 ? (__ffs(g1) + 15)
                    : (__ffs(g2) + 31));
        packed |= ((unsigned long long)m) << (6 * t);
        v0 = (m == l)      ? -INFINITY : v0;
        v1 = (m == l + 16) ? -INFINITY : v1;
        v2 = (m == l + 32) ? -INFINITY : v2;
    }

    // ---- lane i owns proposal i; stage per-group proposal data in LDS ----
    float sattI = 0.f, y1I = 0.f, x1I = 0.f, y2I = 0.f, x2I = 0.f, areaI = 0.f;
    if (l < NP) {
        int mo = (int)((packed >> (6 * l)) & 63ull);
        float av = arow[mo];
        sattI = 1.0f / (1.0f + __expf(-av));
        y1I = brow[mo];
        x1I = brow[mo + MM];
        y2I = brow[mo + 2 * MM];
        x2I = brow[mo + 3 * MM];
        areaI = fmaxf(y2I - y1I, 0.f) * fmaxf(x2I - x1I, 0.f);
        prop[g][l][0] = make_float2(y1I, x1I);
        prop[g][l][1] = make_float2(y2I, x2I);
        prop[g][l][2] = make_float2(areaI, sattI);
    }
    // groups are wave-contained: same-wave LDS ordering handled by lgkmcnt, no barrier

    float cs2_16 = T[2][16].x;      // f2(1.0); score_diff term == cs2_16^10
    float p2 = cs2_16 * cs2_16;
    float p4 = p2 * p2;
    float p8 = p4 * p4;
    float P = p8 * p2;

    const float2* T0 = &T[0][0];
    const float2* T1 = &T[1][0];
    const float2* T2 = &T[2][0];
    const float2* T5 = &T[5][0];
    const float2* T6 = &T[6][0];
    const float2* T7 = &T[7][0];

    // ---- pair loop: lane i computes row i against all j (broadcast LDS reads) ----
    float at[NP];
    float s_i = 0.f, pdAcc = 0.f;
    #pragma unroll
    for (int j = 0; j < NP; ++j) {
        float2 p0 = prop[g][j][0];
        float2 p1 = prop[g][j][1];
        float2 p2v = prop[g][j][2];
        float ty = fmaxf(y1I, p0.x);
        float tx = fmaxf(x1I, p0.y);
        float by = fminf(y2I, p1.x);
        float bx = fminf(x2I, p1.y);
        float inter = fmaxf(by - ty, 0.f) * fmaxf(bx - tx, 0.f);
        float iouv = __fdividef(inter, areaI + p2v.x - inter + 1e-12f);
        float Dm = fmaxf(1.0f - iouv, 0.0f);
        float A = sattI * p2v.y;
        at[j] = pwl_eval(T0, A) * pwl_eval(T1, Dm);
        s_i += pwl_eval(T2, 1.0f - fabsf(sattI - p2v.y)) * P;
        pdAcc += fabsf(pwl_eval(T6, Dm) - 0.5f);
    }

    float inv_i = 1.0f / s_i;
    if (l < NP) invl[g][l] = inv_i;

    float dot = 0.f;
    const float2* ivp = reinterpret_cast<const float2*>(&invl[g][0]);
    #pragma unroll
    for (int jj = 0; jj < NP / 2; ++jj) {
        float2 iv = ivp[jj];
        dot = fmaf(at[2 * jj], iv.x, dot);
        dot = fmaf(at[2 * jj + 1], iv.y, dot);
    }

    float corr = pwl_eval(T0, sattI * sattI) * inv_i;
    float fmask = (l < NP) ? 1.f : 0.f;
    float contrib = fmask * (inv_i * dot + corr);
    float pav = fmask * fabsf(pwl_eval(T5, sattI) - 0.5f);
    float pdv = fmask * pdAcc;

    contrib = rowsum16(contrib);
    pav = rowsum16(pav);
    pdv = rowsum16(pdv);

    // ---- epilogue ----
    float gate = pwl_eval(T7, pav * 0.1f + pdv * 0.01f);
    float cval = sqrtf(contrib + 1e-20f);
    cval = fminf(fmaxf(cval, 0.f), 10.0f);
    float fip = floorf(cval);
    int ipc = (int)fip;
    float frac = cval - fip;
    int i0 = ipc < 10 ? ipc : 10;
    int i1 = (ipc + 1) < 10 ? (ipc + 1) : 10;

    if (valid && l < NP + 1) {
        float val = ((l == i0) ? (1.0f - frac) * gate : 0.f)
                  + ((l == i1) ? frac * gate : 0.f);
        out[(size_t)b * (NP + 1) + l] = val;
    }
}

extern "C" void kernel_launch(void* const* d_in, const int* in_sizes, int n_in,
                              void* d_out, int out_size, void* d_ws, size_t ws_size,
                              hipStream_t stream) {
    const float* boxes = (const float*)d_in[0];
    const float* attention = (const float*)d_in[1];
    const float* fw = (const float*)d_in[2];
    float* out = (float*)d_out;
    int B = in_sizes[1] / MM;   // 32768
    int grid = (B + GPB - 1) / GPB;
    hipLaunchKernelGGL(count_kernel, dim3(grid), dim3(BLOCK), 0, stream,
                       boxes, attention, fw, out, B);
}

// Round 4
// 23.689 us; speedup vs baseline: 1.2264x; 1.0401x over previous
//
#include <hip/hip_runtime.h>
#include <cstdint>
#include <cstddef>

#define MM 36
#define NP 10
#define BLOCK 256
#define GPB (BLOCK / 16)   // 16 batches (groups) per block

// ---- DPP helpers: 16-lane butterfly reduce, zero LDS traffic ----
template<int CTRL>
__device__ __forceinline__ float dpp_movf(float x) {
    return __int_as_float(__builtin_amdgcn_update_dpp(
        0, __float_as_int(x), CTRL, 0xF, 0xF, true));
}
__device__ __forceinline__ float rowmax16(float x) {
    x = fmaxf(x, dpp_movf<0xB1>(x));   // xor 1
    x = fmaxf(x, dpp_movf<0x4E>(x));   // xor 2
    x = fmaxf(x, dpp_movf<0x141>(x));  // row_half_mirror (fold 8)
    x = fmaxf(x, dpp_movf<0x140>(x));  // row_mirror      (fold 16)
    return x;
}
__device__ __forceinline__ float rowsum16(float x) {
    x += dpp_movf<0xB1>(x);
    x += dpp_movf<0x4E>(x);
    x += dpp_movf<0x141>(x);
    x += dpp_movf<0x140>(x);
    return x;
}

// x in [0,1] guaranteed by construction
__device__ __forceinline__ float pwl2(const float2* __restrict__ Trow, float x) {
    float xd = x * 16.0f;
    float fip = floorf(xd);
    float frac = xd - fip;
    int ip = (int)fminf(fip, 16.0f);
    float2 t = Trow[ip];
    return fmaf(frac, t.y, t.x);
}

__global__ __launch_bounds__(BLOCK) void count_kernel(
    const float* __restrict__ boxes,      // [B,4,36]
    const float* __restrict__ attention,  // [B,36]
    const float* __restrict__ fw,         // [8,17]
    float* __restrict__ out,              // [B,11]
    int B)
{
    __shared__ float2 T[8][17];               // (cs[k], nw[min(k+1,16)])
    __shared__ float4 T16[17];                // packed (cs1,nw1',cs6,nw6')
    __shared__ float  boxrow[GPB][4 * MM];    // staged box rows (coalesced fill)
    __shared__ float4 propA[GPB][NP];         // y1,x1,y2,x2
    __shared__ float2 propB[GPB][NP];         // area, satt
    __shared__ __align__(8) float invl[GPB][NP];

    const int tid = threadIdx.x;
    const int lane = tid & 63;
    const int l    = tid & 15;
    const int g    = tid >> 4;
    int b = blockIdx.x * GPB + g;
    const bool valid = (b < B);
    b = valid ? b : (B - 1);

    const float* arow = attention + (size_t)b * MM;
    const float4* brow4 = reinterpret_cast<const float4*>(boxes + (size_t)b * (4 * MM));

    // ---- issue all global loads first (coalesced within each group's row) ----
    float v0 = arow[l];
    float v1 = arow[l + 16];
    float v2 = -INFINITY;
    if (l < 4) v2 = arow[l + 32];
    float4 B0 = brow4[l];
    float4 B1 = brow4[l + 16];
    float4 B2 = make_float4(0.f, 0.f, 0.f, 0.f);
    if (l < 4) B2 = brow4[l + 32];

    // ---- build pwl tables (threads 0..7), pack T1+T6 (threads 0..16) ----
    if (tid < 8) {
        const float* w = fw + tid * 17;
        float aw[17];
        float s = 0.f;
        #pragma unroll
        for (int k = 0; k < 17; ++k) { aw[k] = fabsf(w[k]); s += aw[k]; }
        float nw[17];
        #pragma unroll
        for (int k = 0; k < 17; ++k) nw[k] = aw[k] / s;
        float c = 0.f;
        #pragma unroll
        for (int k = 0; k < 17; ++k) {
            c += nw[k];
            T[tid][k] = make_float2(c, (k < 16) ? nw[k + 1] : nw[16]);
        }
    }
    if (tid < 17) {   // same wave as the builders -> DS in-order, no barrier needed
        float2 a = T[1][tid];
        float2 c = T[6][tid];
        T16[tid] = make_float4(a.x, a.y, c.x, c.y);
    }

    // ---- stage box row into LDS (coalesced b128 writes) ----
    float4* bls = reinterpret_cast<float4*>(&boxrow[g][0]);
    bls[l] = B0;
    bls[l + 16] = B1;
    if (l < 4) bls[l + 32] = B2;

    __syncthreads();

    // ---- top-10: DPP max + ballot argmax; lane t captures (index,value) at round t ----
    const int gbase = tid & 48;
    int mi = 0; float mv = 0.f;
    #pragma unroll
    for (int t = 0; t < NP; ++t) {
        float vm = rowmax16(fmaxf(fmaxf(v0, v1), v2));
        unsigned long long b0 = __ballot(v0 == vm);
        unsigned long long b1 = __ballot(v1 == vm);
        unsigned long long b2 = __ballot(v2 == vm);
        unsigned g0 = (unsigned)(b0 >> gbase) & 0xFFFFu;
        unsigned g1 = (unsigned)(b1 >> gbase) & 0xFFFFu;
        unsigned g2 = (unsigned)(b2 >> gbase) & 0xFFFFu;
        int m = g0 ? (__ffs(g0) - 1)
              : (g1 ? (__ffs(g1) + 15)
                    : (__ffs(g2) + 31));
        if (l == t) { mi = m; mv = vm; }
        v0 = (m == l)      ? -INFINITY : v0;
        v1 = (m == l + 16) ? -INFINITY : v1;
        v2 = (m == l + 32) ? -INFINITY : v2;
    }

    // ---- lane i owns proposal i: gather coords from LDS, stage shared proposal data ----
    float sattI = 0.f, y1I = 0.f, x1I = 0.f, y2I = 0.f, x2I = 0.f, areaI = 0.f;
    if (l < NP) {
        sattI = 1.0f / (1.0f + __expf(-mv));
        y1I = boxrow[g][mi];
        x1I = boxrow[g][mi + MM];
        y2I = boxrow[g][mi + 2 * MM];
        x2I = boxrow[g][mi + 3 * MM];
        areaI = fmaxf(y2I - y1I, 0.f) * fmaxf(x2I - x1I, 0.f);
        propA[g][l] = make_float4(y1I, x1I, y2I, x2I);
        propB[g][l] = make_float2(areaI, sattI);
    }
    // groups are wave-contained: same-wave DS ordering, no barrier

    float cs2_16 = T[2][16].x;      // f2(1.0); zero-score_diff prod == cs2_16^10
    float p2 = cs2_16 * cs2_16;
    float p4 = p2 * p2;
    float p8 = p4 * p4;
    float P = p8 * p2;

    const float2* T0 = &T[0][0];
    const float2* T2 = &T[2][0];
    const float2* T5 = &T[5][0];
    const float2* T7 = &T[7][0];

    // ---- pair loop: lane i vs all j (broadcast LDS reads) ----
    float at[NP];
    float s_i = 0.f, pdAcc = 0.f;
    #pragma unroll
    for (int j = 0; j < NP; ++j) {
        float4 pj = propA[g][j];
        float2 qj = propB[g][j];
        float ty = fmaxf(y1I, pj.x);
        float tx = fmaxf(x1I, pj.y);
        float by = fminf(y2I, pj.z);
        float bx = fminf(x2I, pj.w);
        float inter = fmaxf(by - ty, 0.f) * fmaxf(bx - tx, 0.f);
        float iouv = __fdividef(inter, areaI + qj.x - inter + 1e-12f);
        float Dm = fmaxf(1.0f - iouv, 0.0f);
        float A = sattI * qj.y;
        // shared-x eval of T1 and T6 from the packed float4 table
        float xdD = Dm * 16.0f;
        float fipD = floorf(xdD);
        float frD = xdD - fipD;
        int ipD = (int)fminf(fipD, 16.0f);
        float4 t16 = T16[ipD];
        float f1v = fmaf(frD, t16.y, t16.x);
        float f6v = fabsf(fmaf(frD, t16.w, t16.z) - 0.5f);
        at[j] = pwl2(T0, A) * f1v;
        s_i += pwl2(T2, 1.0f - fabsf(sattI - qj.y)) * P;
        pdAcc += f6v;
    }

    float inv_i = 1.0f / s_i;
    if (l < NP) invl[g][l] = inv_i;

    float dot = 0.f;
    const float2* ivp = reinterpret_cast<const float2*>(&invl[g][0]);
    #pragma unroll
    for (int jj = 0; jj < NP / 2; ++jj) {
        float2 iv = ivp[jj];
        dot = fmaf(at[2 * jj], iv.x, dot);
        dot = fmaf(at[2 * jj + 1], iv.y, dot);
    }

    float corr = pwl2(T0, sattI * sattI) * inv_i;
    float fmask = (l < NP) ? 1.f : 0.f;
    float contrib = fmask * (inv_i * dot + corr);
    float pav = fmask * fabsf(pwl2(T5, sattI) - 0.5f);
    float pdv = fmask * pdAcc;

    contrib = rowsum16(contrib);
    pav = rowsum16(pav);
    pdv = rowsum16(pdv);

    // ---- epilogue ----
    float gate = pwl2(T7, pav * 0.1f + pdv * 0.01f);
    float cval = sqrtf(contrib + 1e-20f);
    cval = fminf(fmaxf(cval, 0.f), 10.0f);
    float fip = floorf(cval);
    int ipc = (int)fip;
    float frac = cval - fip;
    int i0 = ipc < 10 ? ipc : 10;
    int i1 = (ipc + 1) < 10 ? (ipc + 1) : 10;

    if (valid && l < NP + 1) {
        float val = ((l == i0) ? (1.0f - frac) * gate : 0.f)
                  + ((l == i1) ? frac * gate : 0.f);
        out[(size_t)b * (NP + 1) + l] = val;
    }
}

extern "C" void kernel_launch(void* const* d_in, const int* in_sizes, int n_in,
                              void* d_out, int out_size, void* d_ws, size_t ws_size,
                              hipStream_t stream) {
    const float* boxes = (const float*)d_in[0];
    const float* attention = (const float*)d_in[1];
    const float* fw = (const float*)d_in[2];
    float* out = (float*)d_out;
    int B = in_sizes[1] / MM;   // 32768
    int grid = (B + GPB - 1) / GPB;
    hipLaunchKernelGGL(count_kernel, dim3(grid), dim3(BLOCK), 0, stream,
                       boxes, attention, fw, out, B);
}